// Round 10
// baseline (207.469 us; speedup 1.0000x reference)
//
#include <hip/hip_runtime.h>
#include <math.h>

#define N_INIT 20000
#define LVLS   32
#define PP     1024
#define DD     64
#define DEE    128
#define N_TOT  (N_INIT + LVLS * PP)   // 52768
#define ND     (LVLS * PP)            // 32768 derived nodes
#define NBLK   512                    // 2 blocks/CU, co-residency proven r8/r9
#define NTHR   256
#define NTILES ((N_TOT + 63) / 64)    // 825 eval tiles

// ws layout:
// [0,128)  ctl: acc_i[4]@0, acc_f@16, init_done@20, fin_done@24
// [128, 128+ND*DD*4)   dstore  (memset 0xFF each call: negative-NaN sentinel)
#define DSTORE_OFF 128

typedef unsigned long long ull;
union F2U { ull u; float2 f; };
#define SENT_MASK 0x8000000080000000ULL
#define SIGN_CLR  0x7FFFFFFF7FFFFFFFULL

// ---- device-coherent accessors (AGENT scope), proven r5-r9 ----
__device__ __forceinline__ int ldi(const int* p) {
    return __hip_atomic_load(p, __ATOMIC_RELAXED, __HIP_MEMORY_SCOPE_AGENT);
}
__device__ __forceinline__ float ldf(const float* p) {
    return __hip_atomic_load(p, __ATOMIC_RELAXED, __HIP_MEMORY_SCOPE_AGENT);
}
__device__ __forceinline__ ull ldull(const ull* p) {
    return __hip_atomic_load(p, __ATOMIC_RELAXED, __HIP_MEMORY_SCOPE_AGENT);
}
__device__ __forceinline__ void stull(ull* p, ull v) {
    __hip_atomic_store(p, v, __ATOMIC_RELAXED, __HIP_MEMORY_SCOPE_AGENT);
}
__device__ __forceinline__ void vm0() {
    asm volatile("s_waitcnt vmcnt(0)" ::: "memory");
}
__device__ __forceinline__ float softplusf(float x) {
    return fmaxf(x, 0.f) + log1pf(expf(-fabsf(x)));
}
// speculative load of a published float2: retry while any sign bit set
__device__ __forceinline__ float2 ld_pub(const ull* p) {
    F2U cv;
    cv.u = ldull(p);
    while (cv.u & SENT_MASK) {
        __builtin_amdgcn_s_sleep(1);
        cv.u = ldull(p);
    }
    return cv.f;
}

__global__ __launch_bounds__(NTHR, 2) void persist6(
    const int* __restrict__ thax, const int* __restrict__ parents,
    const int* __restrict__ rules, const int* __restrict__ sel_mask,
    const int* __restrict__ good_mask, const float* __restrict__ init_table,
    const float* __restrict__ W_rule, const float* __restrict__ b_rule,
    const float* __restrict__ W1, const float* __restrict__ b1,
    const float* __restrict__ w2, const float* __restrict__ b2,
    char* __restrict__ ws, float* __restrict__ out)
{
    int*   acc_i     = (int*)ws;
    float* acc_f     = (float*)(ws + 16);
    int*   init_done = (int*)(ws + 20);
    int*   fin_done  = (int*)(ws + 24);
    ull*   dstore_u  = (ull*)(ws + DSTORE_OFF);

    const int b = blockIdx.x, t = threadIdx.x;
    const int lane = t & 63, wv = t >> 6;

    __shared__ float sS[64][DD];     // 16 KB (eval)
    __shared__ float logitL[64];

    if (wv >= 2) {
        // ---------------- waves 2-3: mask counts (block's 256-idx range) ----------------
        int i0 = b * NTHR + (wv - 2) * 128 + lane;
        int cs = 0, cg = 0;
#pragma unroll
        for (int k = 0; k < 2; ++k) {
            int idx = i0 + k * 64;
            if (idx < N_TOT) {
                bool sel  = sel_mask[idx] > 0;
                bool good = sel && good_mask[idx] > 0;
                cs += sel ? 1 : 0;
                cg += good ? 1 : 0;
            }
        }
#pragma unroll
        for (int off = 32; off; off >>= 1) {
            cs += __shfl_down(cs, off, 64);
            cg += __shfl_down(cg, off, 64);
        }
        if (lane == 0) {
            if (cg) atomicAdd(&acc_i[0], cg);
            if (cs) atomicAdd(&acc_i[1], cs);
            vm0();                          // adds at coherence point first
            atomicAdd(init_done, 1);
        }
    } else {
        // ---------------- waves 0-1: barrier-free level chain, 1 node/wave ----------------
        const int nd = b * 2 + wv;                 // node within each level
        const int q  = lane & 15, r = lane >> 4;
        const int rq = r >> 1,   rb = r & 1;
        const int prow = lane >> 5, pel = lane & 31; // lane's (parent row, float2 elem)

        // prologue: level-0 parents are all init nodes (< N_INIT by construction)
        F2U cur; const ull* cur_ptr = nullptr; bool curd = false;
        {
            int pid = parents[(size_t)nd * 2 + prow];
            cur.f = ((const float2*)init_table)[(size_t)thax[pid] * 32 + pel];
        }

        for (int l = 0; l < LVLS; ++l) {
            // validate current level's gathered data (spin only on fresh parents)
            if (curd) {
                while (cur.u & SENT_MASK) {
                    __builtin_amdgcn_s_sleep(1);
                    cur.u = ldull(cur_ptr);
                }
            }
            // early-issue next level's gather (overlaps with compute below)
            F2U nxt; const ull* nxt_ptr = nullptr; bool nxtd = false;
            if (l + 1 < LVLS) {
                int npid = parents[((size_t)(l + 1) * PP + nd) * 2 + prow];
                if (npid < N_INIT) {
                    nxt.f = ((const float2*)init_table)[(size_t)thax[npid] * 32 + pel];
                } else {
                    nxt_ptr = &dstore_u[(size_t)(npid - N_INIT) * 32 + pel];
                    nxt.u = ldull(nxt_ptr);
                    nxtd = true;
                }
            } else {
                nxt.f = make_float2(0.f, 0.f);
            }
            // compute: pe[e] broadcast via shfl (srcLane = e>>1, component = r&1)
            const int ru = rules[l * PP + nd];
            const float4* __restrict__ W4 = (const float4*)W_rule + (size_t)ru * 2048;
            float4 acc = make_float4(0.f, 0.f, 0.f, 0.f);
#pragma unroll
            for (int i = 0; i < 32; ++i) {
                float lo = __shfl(cur.f.x, 2 * i + rq, 64);
                float hi = __shfl(cur.f.y, 2 * i + rq, 64);
                float s  = rb ? hi : lo;
                float4 w = W4[(i * 4 + r) * 16 + q];
                acc.x = fmaf(s, w.x, acc.x);
                acc.y = fmaf(s, w.y, acc.y);
                acc.z = fmaf(s, w.z, acc.z);
                acc.w = fmaf(s, w.w, acc.w);
            }
#pragma unroll
            for (int off = 16; off <= 32; off <<= 1) {
                acc.x += __shfl_xor(acc.x, off, 64);
                acc.y += __shfl_xor(acc.y, off, 64);
                acc.z += __shfl_xor(acc.z, off, 64);
                acc.w += __shfl_xor(acc.w, off, 64);
            }
            if (r == 0) {      // 16 lanes publish 4 floats each (sign-cleared)
                float4 bb = ((const float4*)b_rule)[ru * 16 + q];
                F2U c0, c1;
                c0.f.x = fmaxf(acc.x + bb.x, 0.f);
                c0.f.y = fmaxf(acc.y + bb.y, 0.f);
                c1.f.x = fmaxf(acc.z + bb.z, 0.f);
                c1.f.y = fmaxf(acc.w + bb.w, 0.f);
                c0.u &= SIGN_CLR;
                c1.u &= SIGN_CLR;
                ull* dp = &dstore_u[((size_t)l * PP + nd) * 32 + 2 * q];
                stull(dp, c0.u);
                stull(dp + 1, c1.u);
            }
            cur = nxt; cur_ptr = nxt_ptr; curd = nxtd;
        }
    }

    // ---------------- gate on mask counts (all waves) ----------------
    while (ldi(init_done) < 2 * NBLK) __builtin_amdgcn_s_sleep(1);
    const int ng = ldi(&acc_i[0]);
    const int ns = ldi(&acc_i[1]);
    const int nn = ns - ng;
    const float pos_w = ng > 0 ? 0.85f / (float)ng : 1.0f;
    const float neg_w = nn > 0 ? 0.15f / (float)nn : 1.0f;

    // ---------------- eval + loss (r9-verbatim block-wide math) ----------------
    const int g  = t & 31;
    const int n0 = t >> 5;
    const float4* __restrict__ W14 = (const float4*)W1;
    const float4 b1v = ((const float4*)b1)[g];
    const float4 w2v = ((const float4*)w2)[g];
    const float  b2v = b2[0];

    float loss = 0.f;
    int cp = 0, cn = 0;

    for (int tile = b; tile < NTILES; tile += NBLK) {
        const int base = tile * 64;
        const int nv = (N_TOT - base < 64) ? (N_TOT - base) : 64;
        for (int idx = t; idx < 64 * 32; idx += NTHR) {
            int n = idx >> 5, j = idx & 31;
            int node = base + n;
            float2 v = make_float2(0.f, 0.f);
            if (n < nv) {
                if (node < N_INIT)
                    v = ((const float2*)init_table)[(size_t)thax[node] * 32 + j];
                else
                    v = ld_pub(&dstore_u[(size_t)(node - N_INIT) * 32 + j]);
            }
            ((float2*)sS[n])[j] = v;
        }
        __syncthreads();

        float4 a[8];
#pragma unroll
        for (int k = 0; k < 8; ++k) a[k] = b1v;
#pragma unroll
        for (int d4 = 0; d4 < 16; ++d4) {
            float4 w0  = W14[(d4 * 4 + 0) * 32 + g];
            float4 w1  = W14[(d4 * 4 + 1) * 32 + g];
            float4 w2q = W14[(d4 * 4 + 2) * 32 + g];
            float4 w3  = W14[(d4 * 4 + 3) * 32 + g];
#pragma unroll
            for (int k = 0; k < 8; ++k) {
                float4 s = ((const float4*)sS[n0 + 8 * k])[d4];
                a[k].x = fmaf(s.x, w0.x, a[k].x); a[k].y = fmaf(s.x, w0.y, a[k].y);
                a[k].z = fmaf(s.x, w0.z, a[k].z); a[k].w = fmaf(s.x, w0.w, a[k].w);
                a[k].x = fmaf(s.y, w1.x, a[k].x); a[k].y = fmaf(s.y, w1.y, a[k].y);
                a[k].z = fmaf(s.y, w1.z, a[k].z); a[k].w = fmaf(s.y, w1.w, a[k].w);
                a[k].x = fmaf(s.z, w2q.x, a[k].x); a[k].y = fmaf(s.z, w2q.y, a[k].y);
                a[k].z = fmaf(s.z, w2q.z, a[k].z); a[k].w = fmaf(s.z, w2q.w, a[k].w);
                a[k].x = fmaf(s.w, w3.x, a[k].x); a[k].y = fmaf(s.w, w3.y, a[k].y);
                a[k].z = fmaf(s.w, w3.z, a[k].z); a[k].w = fmaf(s.w, w3.w, a[k].w);
            }
        }
        float p[8];
#pragma unroll
        for (int k = 0; k < 8; ++k) {
            p[k] = fmaxf(a[k].x, 0.f) * w2v.x + fmaxf(a[k].y, 0.f) * w2v.y +
                   fmaxf(a[k].z, 0.f) * w2v.z + fmaxf(a[k].w, 0.f) * w2v.w;
#pragma unroll
            for (int off = 1; off < 32; off <<= 1)
                p[k] += __shfl_xor(p[k], off, 32);
        }
        if (g == 0) {
#pragma unroll
            for (int k = 0; k < 8; ++k)
                logitL[n0 + 8 * k] = p[k] + b2v;
        }
        __syncthreads();

        if (t < 64) {
            int node = base + t;
            bool valid = t < nv;
            float lg = logitL[t];
            bool sel  = valid && sel_mask[node] > 0;
            bool good = sel && good_mask[node] > 0;
            float bce = softplusf(lg) - lg * (good ? 1.f : 0.f);
            float w   = (good ? pos_w : neg_w) * (sel ? 1.f : 0.f);
            loss += valid ? w * bce : 0.f;
            cp += (good && lg >= 0.f) ? 1 : 0;
            cn += (sel && !good && lg < 0.f) ? 1 : 0;
        }
        __syncthreads();
    }

    // ---------------- reduce + finalize (r9 verbatim) ----------------
    if (t < 64) {
        float c = loss;
        int cpp = cp, cnn = cn;
#pragma unroll
        for (int off = 32; off; off >>= 1) {
            c   += __shfl_down(c, off, 64);
            cpp += __shfl_down(cpp, off, 64);
            cnn += __shfl_down(cnn, off, 64);
        }
        if (t == 0) {
            atomicAdd(acc_f, c);
            if (cpp) atomicAdd(&acc_i[2], cpp);
            if (cnn) atomicAdd(&acc_i[3], cnn);
            vm0();
            int d = atomicAdd(fin_done, 1);
            if (d == NBLK - 1) {
                int ng2 = ldi(&acc_i[0]);
                int ns2 = ldi(&acc_i[1]);
                int cp2 = ldi(&acc_i[2]);
                int cn2 = ldi(&acc_i[3]);
                float lf = ldf(acc_f);
                int nn2 = ns2 - ng2;
                out[0] = lf;
                out[1] = ng2 > 0 ? (float)cp2 / (float)ng2 : 1.0f;
                out[2] = nn2 > 0 ? (float)cn2 / (float)nn2 : 1.0f;
            }
        }
    }
}

extern "C" void kernel_launch(void* const* d_in, const int* in_sizes, int n_in,
                              void* d_out, int out_size, void* d_ws, size_t ws_size,
                              hipStream_t stream) {
    const int*   thax       = (const int*)d_in[0];
    const int*   parents    = (const int*)d_in[1];
    const int*   rules      = (const int*)d_in[2];
    const int*   sel_mask   = (const int*)d_in[3];
    const int*   good_mask  = (const int*)d_in[4];
    const float* init_table = (const float*)d_in[5];
    const float* W_rule     = (const float*)d_in[6];
    const float* b_rule     = (const float*)d_in[7];
    const float* W1         = (const float*)d_in[8];
    const float* b1         = (const float*)d_in[9];
    const float* w2         = (const float*)d_in[10];
    const float* b2         = (const float*)d_in[11];

    // ctl -> 0 ; dstore -> 0xFF (negative-NaN sentinel, sign bit 1)
    hipMemsetAsync(d_ws, 0, 128, stream);
    hipMemsetAsync((char*)d_ws + DSTORE_OFF, 0xFF, (size_t)ND * DD * 4, stream);

    persist6<<<NBLK, NTHR, 0, stream>>>(
        thax, parents, rules, sel_mask, good_mask, init_table,
        W_rule, b_rule, W1, b1, w2, b2,
        (char*)d_ws, (float*)d_out);
}

// Round 11
// 176.905 us; speedup vs baseline: 1.1728x; 1.1728x over previous
//
#include <hip/hip_runtime.h>
#include <math.h>

#define N_INIT 20000
#define LVLS   32
#define PP     1024
#define DD     64
#define DEE    128
#define N_TOT  (N_INIT + LVLS * PP)   // 52768
#define ND     (LVLS * PP)            // 32768 derived nodes
#define NBLK   512                    // 2 blocks/CU, co-residency proven r8/r9
#define NTHR   256
#define NPB    2                      // nodes per block per level (512*2 = 1024)
#define NTILES ((N_TOT + 63) / 64)    // 825 eval tiles

// ws layout:
// [0,128)  ctl: acc_i[4]@0, acc_f@16, init_done@20, fin_done@24
// [128, 128+ND*DD*4)   dstore  (memset 0xFF each call: negative-NaN sentinel)
#define DSTORE_OFF 128

typedef unsigned long long ull;
union F2U { ull u; float2 f; };
#define SENT_MASK 0x8000000080000000ULL
#define SIGN_CLR  0x7FFFFFFF7FFFFFFFULL

// ---- device-coherent accessors (AGENT scope), proven r5-r9 ----
__device__ __forceinline__ int ldi(const int* p) {
    return __hip_atomic_load(p, __ATOMIC_RELAXED, __HIP_MEMORY_SCOPE_AGENT);
}
__device__ __forceinline__ float ldf(const float* p) {
    return __hip_atomic_load(p, __ATOMIC_RELAXED, __HIP_MEMORY_SCOPE_AGENT);
}
__device__ __forceinline__ ull ldull(const ull* p) {
    return __hip_atomic_load(p, __ATOMIC_RELAXED, __HIP_MEMORY_SCOPE_AGENT);
}
__device__ __forceinline__ void stull(ull* p, ull v) {
    __hip_atomic_store(p, v, __ATOMIC_RELAXED, __HIP_MEMORY_SCOPE_AGENT);
}
__device__ __forceinline__ void vm0() {
    asm volatile("s_waitcnt vmcnt(0)" ::: "memory");
}
__device__ __forceinline__ float softplusf(float x) {
    return fmaxf(x, 0.f) + log1pf(expf(-fabsf(x)));
}
// hybrid read of a published float2: fast cached try, coherent spin fallback.
// Safe even if the 8B load tears: validity is per-32-bit sign bit, and any
// sentinel half routes to the sc1 path (which bypasses stale L1/L2; r9-proven).
__device__ __forceinline__ float2 ld_hyb(const ull* p) {
    F2U cv;
    cv.u = *p;                         // normal cached load (L1/L2/MALL)
    if (cv.u & SENT_MASK) {
        cv.u = ldull(p);               // coherent retry
        while (cv.u & SENT_MASK) {
            __builtin_amdgcn_s_sleep(1);
            cv.u = ldull(p);
        }
    }
    return cv.f;
}

__global__ __launch_bounds__(NTHR, 2) void persist7(
    const int* __restrict__ thax, const int* __restrict__ parents,
    const int* __restrict__ rules, const int* __restrict__ sel_mask,
    const int* __restrict__ good_mask, const float* __restrict__ init_table,
    const float* __restrict__ W_rule, const float* __restrict__ b_rule,
    const float* __restrict__ W1, const float* __restrict__ b1,
    const float* __restrict__ w2, const float* __restrict__ b2,
    char* __restrict__ ws, float* __restrict__ out)
{
    int*   acc_i     = (int*)ws;
    float* acc_f     = (float*)(ws + 16);
    int*   init_done = (int*)(ws + 20);
    int*   fin_done  = (int*)(ws + 24);
    ull*   dstore_u  = (ull*)(ws + DSTORE_OFF);

    const int b = blockIdx.x, t = threadIdx.x;
    const int lane = t & 63, wv = t >> 6;

    __shared__ float peL[NPB][2 * DD];      // 1 KB
    __shared__ float partial[2][4][DD];     // 2 KB (double-buffered by level parity)
    __shared__ float sS[64][DD];            // 16 KB (eval)
    __shared__ float logitL[64];

    // ---------------- phase 1: mask counts (r9 verbatim) ----------------
    {
        int idx = b * NTHR + t;
        bool v = idx < N_TOT;
        bool sel  = v && sel_mask[idx] > 0;
        bool good = sel && good_mask[idx] > 0;
        unsigned long long ms = __ballot(sel), mg = __ballot(good);
        if (lane == 0) {
            if (mg) atomicAdd(&acc_i[0], (int)__popcll(mg));
            if (ms) atomicAdd(&acc_i[1], (int)__popcll(ms));
        }
    }
    vm0();
    __syncthreads();
    if (t == 0) atomicAdd(init_done, 1);

    // ---------------- phase 2: 32 levels, 2 barriers/level ----------------
    const int nb0 = b * NPB;
    // prologue: gather level 0 (parents all < N_INIT by construction)
    if (t < 128) {
        int row = t >> 5, j = t & 31;
        int pid = parents[(size_t)nb0 * 2 + row];
        float2 v = ((const float2*)init_table)[(size_t)thax[pid] * 32 + j];
        ((float2*)&peL[row >> 1][(row & 1) * DD])[j] = v;
    }

    for (int l = 0; l < LVLS; ++l) {
        __syncthreads();                       // peL ready
        // compute: waves {0,1}->node 0, {2,3}->node 1; half = wv&1 covers 64 rows
        {
            const int nv = wv >> 1, half = wv & 1;
            const int ru = rules[l * PP + nb0 + nv];
            const float4* __restrict__ W4 =
                (const float4*)W_rule + (size_t)ru * 2048 + (size_t)half * 64 * 16;
            const int q = lane & 15, r = lane >> 4;
            const float* pk = &peL[nv][half * DD];
            float4 acc = make_float4(0.f, 0.f, 0.f, 0.f);
#pragma unroll
            for (int i = 0; i < 16; ++i) {
                float4 w = W4[(i * 4 + r) * 16 + q];
                float  s = pk[i * 4 + r];
                acc.x = fmaf(s, w.x, acc.x);
                acc.y = fmaf(s, w.y, acc.y);
                acc.z = fmaf(s, w.z, acc.z);
                acc.w = fmaf(s, w.w, acc.w);
            }
#pragma unroll
            for (int off = 16; off <= 32; off <<= 1) {
                acc.x += __shfl_xor(acc.x, off, 64);
                acc.y += __shfl_xor(acc.y, off, 64);
                acc.z += __shfl_xor(acc.z, off, 64);
                acc.w += __shfl_xor(acc.w, off, 64);
            }
            if (r == 0) *(float4*)&partial[l & 1][wv][4 * q] = acc;
        }
        __syncthreads();                       // partial ready
        // publish (fire-and-forget sc1) ...
        if (t < 64) {
            const int nv = t >> 5;
            const int j2 = t & 31;
            const int jj = j2 * 2;
            const int ru = rules[l * PP + nb0 + nv];
            float h0 = partial[l & 1][2 * nv][jj]     + partial[l & 1][2 * nv + 1][jj]
                     + b_rule[ru * DD + jj];
            float h1 = partial[l & 1][2 * nv][jj + 1] + partial[l & 1][2 * nv + 1][jj + 1]
                     + b_rule[ru * DD + jj + 1];
            F2U cv;
            cv.f.x = fmaxf(h0, 0.f);
            cv.f.y = fmaxf(h1, 0.f);
            cv.u &= SIGN_CLR;          // published sign bits must be 0
            stull(&dstore_u[((size_t)l * PP + nb0 + nv) * 32 + j2], cv.u);
        }
        // ... overlapped with next level's gather (hybrid reads)
        if (l + 1 < LVLS && t < 128) {
            int row = t >> 5, j = t & 31;
            int pid = parents[((size_t)(l + 1) * PP + nb0) * 2 + row];
            float2 v;
            if (pid < N_INIT)
                v = ((const float2*)init_table)[(size_t)thax[pid] * 32 + j];
            else
                v = ld_hyb(&dstore_u[(size_t)(pid - N_INIT) * 32 + j]);
            ((float2*)&peL[row >> 1][(row & 1) * DD])[j] = v;
        }
    }

    // ---------------- phase 3: gate on mask counts ----------------
    if (t == 0) { while (ldi(init_done) < NBLK) __builtin_amdgcn_s_sleep(1); }
    __syncthreads();
    const int ng = ldi(&acc_i[0]);
    const int ns = ldi(&acc_i[1]);
    const int nn = ns - ng;
    const float pos_w = ng > 0 ? 0.85f / (float)ng : 1.0f;
    const float neg_w = nn > 0 ? 0.15f / (float)nn : 1.0f;

    // ---------------- phase 4: eval + loss (r9 math, hybrid reads) ----------------
    const int g  = t & 31;
    const int n0 = t >> 5;
    const float4* __restrict__ W14 = (const float4*)W1;
    const float4 b1v = ((const float4*)b1)[g];
    const float4 w2v = ((const float4*)w2)[g];
    const float  b2v = b2[0];

    float loss = 0.f;
    int cp = 0, cn = 0;

    for (int tile = b; tile < NTILES; tile += NBLK) {
        const int base = tile * 64;
        const int nv = (N_TOT - base < 64) ? (N_TOT - base) : 64;
        for (int idx = t; idx < 64 * 32; idx += NTHR) {
            int n = idx >> 5, j = idx & 31;
            int node = base + n;
            float2 v = make_float2(0.f, 0.f);
            if (n < nv) {
                if (node < N_INIT)
                    v = ((const float2*)init_table)[(size_t)thax[node] * 32 + j];
                else
                    v = ld_hyb(&dstore_u[(size_t)(node - N_INIT) * 32 + j]);
            }
            ((float2*)sS[n])[j] = v;
        }
        __syncthreads();

        float4 a[8];
#pragma unroll
        for (int k = 0; k < 8; ++k) a[k] = b1v;
#pragma unroll
        for (int d4 = 0; d4 < 16; ++d4) {
            float4 w0  = W14[(d4 * 4 + 0) * 32 + g];
            float4 w1  = W14[(d4 * 4 + 1) * 32 + g];
            float4 w2q = W14[(d4 * 4 + 2) * 32 + g];
            float4 w3  = W14[(d4 * 4 + 3) * 32 + g];
#pragma unroll
            for (int k = 0; k < 8; ++k) {
                float4 s = ((const float4*)sS[n0 + 8 * k])[d4];
                a[k].x = fmaf(s.x, w0.x, a[k].x); a[k].y = fmaf(s.x, w0.y, a[k].y);
                a[k].z = fmaf(s.x, w0.z, a[k].z); a[k].w = fmaf(s.x, w0.w, a[k].w);
                a[k].x = fmaf(s.y, w1.x, a[k].x); a[k].y = fmaf(s.y, w1.y, a[k].y);
                a[k].z = fmaf(s.y, w1.z, a[k].z); a[k].w = fmaf(s.y, w1.w, a[k].w);
                a[k].x = fmaf(s.z, w2q.x, a[k].x); a[k].y = fmaf(s.z, w2q.y, a[k].y);
                a[k].z = fmaf(s.z, w2q.z, a[k].z); a[k].w = fmaf(s.z, w2q.w, a[k].w);
                a[k].x = fmaf(s.w, w3.x, a[k].x); a[k].y = fmaf(s.w, w3.y, a[k].y);
                a[k].z = fmaf(s.w, w3.z, a[k].z); a[k].w = fmaf(s.w, w3.w, a[k].w);
            }
        }
        float p[8];
#pragma unroll
        for (int k = 0; k < 8; ++k) {
            p[k] = fmaxf(a[k].x, 0.f) * w2v.x + fmaxf(a[k].y, 0.f) * w2v.y +
                   fmaxf(a[k].z, 0.f) * w2v.z + fmaxf(a[k].w, 0.f) * w2v.w;
#pragma unroll
            for (int off = 1; off < 32; off <<= 1)
                p[k] += __shfl_xor(p[k], off, 32);
        }
        if (g == 0) {
#pragma unroll
            for (int k = 0; k < 8; ++k)
                logitL[n0 + 8 * k] = p[k] + b2v;
        }
        __syncthreads();

        if (t < 64) {
            int node = base + t;
            bool valid = t < nv;
            float lg = logitL[t];
            bool sel  = valid && sel_mask[node] > 0;
            bool good = sel && good_mask[node] > 0;
            float bce = softplusf(lg) - lg * (good ? 1.f : 0.f);
            float w   = (good ? pos_w : neg_w) * (sel ? 1.f : 0.f);
            loss += valid ? w * bce : 0.f;
            cp += (good && lg >= 0.f) ? 1 : 0;
            cn += (sel && !good && lg < 0.f) ? 1 : 0;
        }
        __syncthreads();
    }

    // ---------------- phase 5: reduce + finalize (r9 verbatim) ----------------
    if (t < 64) {
        float c = loss;
        int cpp = cp, cnn = cn;
#pragma unroll
        for (int off = 32; off; off >>= 1) {
            c   += __shfl_down(c, off, 64);
            cpp += __shfl_down(cpp, off, 64);
            cnn += __shfl_down(cnn, off, 64);
        }
        if (t == 0) {
            atomicAdd(acc_f, c);
            if (cpp) atomicAdd(&acc_i[2], cpp);
            if (cnn) atomicAdd(&acc_i[3], cnn);
            vm0();
            int d = atomicAdd(fin_done, 1);
            if (d == NBLK - 1) {
                int ng2 = ldi(&acc_i[0]);
                int ns2 = ldi(&acc_i[1]);
                int cp2 = ldi(&acc_i[2]);
                int cn2 = ldi(&acc_i[3]);
                float lf = ldf(acc_f);
                int nn2 = ns2 - ng2;
                out[0] = lf;
                out[1] = ng2 > 0 ? (float)cp2 / (float)ng2 : 1.0f;
                out[2] = nn2 > 0 ? (float)cn2 / (float)nn2 : 1.0f;
            }
        }
    }
}

extern "C" void kernel_launch(void* const* d_in, const int* in_sizes, int n_in,
                              void* d_out, int out_size, void* d_ws, size_t ws_size,
                              hipStream_t stream) {
    const int*   thax       = (const int*)d_in[0];
    const int*   parents    = (const int*)d_in[1];
    const int*   rules      = (const int*)d_in[2];
    const int*   sel_mask   = (const int*)d_in[3];
    const int*   good_mask  = (const int*)d_in[4];
    const float* init_table = (const float*)d_in[5];
    const float* W_rule     = (const float*)d_in[6];
    const float* b_rule     = (const float*)d_in[7];
    const float* W1         = (const float*)d_in[8];
    const float* b1         = (const float*)d_in[9];
    const float* w2         = (const float*)d_in[10];
    const float* b2         = (const float*)d_in[11];

    // ctl -> 0 ; dstore -> 0xFF (negative-NaN sentinel, sign bit 1)
    hipMemsetAsync(d_ws, 0, 128, stream);
    hipMemsetAsync((char*)d_ws + DSTORE_OFF, 0xFF, (size_t)ND * DD * 4, stream);

    persist7<<<NBLK, NTHR, 0, stream>>>(
        thax, parents, rules, sel_mask, good_mask, init_table,
        W_rule, b_rule, W1, b1, w2, b2,
        (char*)d_ws, (float*)d_out);
}